// Round 12
// baseline (145.629 us; speedup 1.0000x reference)
//
#include <hip/hip_runtime.h>
#include <hip/hip_bf16.h>
#include <stdint.h>

typedef __attribute__((ext_vector_type(8))) short short8;
typedef __attribute__((ext_vector_type(4))) float f32x4;
typedef __attribute__((ext_vector_type(16))) float f32x16;
typedef __attribute__((ext_vector_type(2))) int int2v;
typedef unsigned short u16;
typedef unsigned int u32;

// B=2, H=16, L=2048, Dh=64, Dm=1024, M=B*L=4096, K=1024

#define WAIT_VM12() do { asm volatile("s_waitcnt vmcnt(12)" ::: "memory"); \
                         __builtin_amdgcn_sched_barrier(0); } while (0)
#define WAIT_VM8()  do { asm volatile("s_waitcnt vmcnt(8)" ::: "memory"); \
                         __builtin_amdgcn_sched_barrier(0); } while (0)
#define WAIT_VM0()  do { asm volatile("s_waitcnt vmcnt(0)" ::: "memory"); \
                         __builtin_amdgcn_sched_barrier(0); } while (0)
#define BARRIER()   do { __builtin_amdgcn_s_barrier(); \
                         __builtin_amdgcn_sched_barrier(0); } while (0)
#define LGKM0_BAR() do { asm volatile("s_waitcnt lgkmcnt(0)" ::: "memory"); \
                         __builtin_amdgcn_s_barrier(); \
                         __builtin_amdgcn_sched_barrier(0); } while (0)

// LDS row swizzle: 2-way max bank aliasing (conflict-free, validated R11)
#define FSWZ(r) (((r) ^ ((r) >> 3)) & 7)

__device__ __forceinline__ u16 bf16rne(float f) {
  u32 u = __builtin_bit_cast(u32, f);
  u += 0x7FFFu + ((u >> 16) & 1u);
  return (u16)(u >> 16);
}

__device__ __forceinline__ u32 cvtpk(float lo, float hi) {
  u32 r;
  asm("v_cvt_pk_bf16_f32 %0, %1, %2" : "=v"(r) : "v"(lo), "v"(hi));
  return r;
}

__device__ __forceinline__ void gl_lds16(const u16* g, u16* l) {
  __builtin_amdgcn_global_load_lds((const __attribute__((address_space(1))) void*)g,
                                   (__attribute__((address_space(3))) void*)l, 16, 0, 0);
}

// ---------------- cast kernel (weights only) ----------------
struct CastArgs {
  const float* src[4];
  u16* dst[4];
  int n4[4];
};

__global__ void cast_all(CastArgs a) {
  const int id = blockIdx.y;
  const float* __restrict__ s = a.src[id];
  u16* __restrict__ d = a.dst[id];
  const int stride = gridDim.x * blockDim.x;
  const int i0 = blockIdx.x * blockDim.x + threadIdx.x;
  if (id < 3) {
    const int n4 = a.n4[id];
    for (int i = i0; i < n4; i += stride) {
      float4 v = ((const float4*)s)[i];
      u32 lo = (u32)bf16rne(v.x) | ((u32)bf16rne(v.y) << 16);
      u32 hi = (u32)bf16rne(v.z) | ((u32)bf16rne(v.w) << 16);
      ((uint2*)d)[i] = make_uint2(lo, hi);
    }
  } else {
    // W_O permute: dst[n][h*64+dd] = src[n][dd*16+h]
    const int n = a.n4[3];
    for (int i = i0; i < n; i += stride) {
      int row = i >> 10, c = i & 1023;
      int hh = c >> 6, dd = c & 63;
      d[i] = bf16rne(s[(row << 10) + dd * 16 + hh]);
    }
  }
}

// ---------------- fused cast+GEMM: As SINGLE-buffered (48KB LDS -> 3 blocks/CU) ------------
struct ProjFArgs { const float* A[3]; const u16* W[3]; u16* D[3]; float scale[3]; };

__global__ __launch_bounds__(256, 2) void gemm_projf(ProjFArgs pa) {
  const int bid = blockIdx.x;                       // 0..767
  const int grp = ((bid >> 6) << 3) | (bid & 7);    // (proj,bm) group, same XCD for its 8 bn
  const int bn = ((bid >> 3) & 7) * 128;
  const int z = grp >> 5;
  const int bm = (grp & 31) * 128;
  const float* __restrict__ A = pa.A[z];
  const u16* __restrict__ Bw = pa.W[z];
  u16* __restrict__ D = pa.D[z];
  const float ascale = pa.scale[z];
  const int epi = (z == 2) ? 1 : 0;

  const int tid = threadIdx.x, lane = tid & 63, w = tid >> 6;
  const int wr = w >> 1, wc = w & 1;
  __shared__ __align__(16) u16 As[128 * 64];        // single buffer: regs are the 2nd buffer
  __shared__ __align__(16) u16 Bs[2][128 * 64];

  f32x4 acc[4][4];
#pragma unroll
  for (int m = 0; m < 4; ++m)
#pragma unroll
    for (int n = 0; n < 4; ++n) acc[m][n] = (f32x4){0.f, 0.f, 0.f, 0.f};

  struct ARegs { float4 v[8]; };
  ARegs RA, RB;

  auto STAGE_A = [&](int kt, ARegs& R) {
#pragma unroll
    for (int i = 0; i < 4; ++i) {
      int c = tid + i * 256;
      int row = c >> 3;
      int col = (((c & 7) ^ (row & 7)) << 3);
      const float* src = A + (size_t)(bm + row) * 1024 + kt * 64 + col;
      R.v[2 * i] = *(const float4*)(src);
      R.v[2 * i + 1] = *(const float4*)(src + 4);
    }
  };
  auto WRITE_A = [&](ARegs& R) {
#pragma unroll
    for (int i = 0; i < 4; ++i) {
      int c = tid + i * 256;
      u32 p0 = (u32)bf16rne(R.v[2 * i].x) | ((u32)bf16rne(R.v[2 * i].y) << 16);
      u32 p1 = (u32)bf16rne(R.v[2 * i].z) | ((u32)bf16rne(R.v[2 * i].w) << 16);
      u32 p2 = (u32)bf16rne(R.v[2 * i + 1].x) | ((u32)bf16rne(R.v[2 * i + 1].y) << 16);
      u32 p3 = (u32)bf16rne(R.v[2 * i + 1].z) | ((u32)bf16rne(R.v[2 * i + 1].w) << 16);
      *(uint4*)&As[c * 8] = make_uint4(p0, p1, p2, p3);
    }
  };
  auto STAGE_B = [&](int kt, int b) {
#pragma unroll
    for (int i = 0; i < 4; ++i) {
      int c = tid + i * 256;
      int row = c >> 3;
      int swz = (((c & 7) ^ (row & 7)) << 3);
      gl_lds16(Bw + (size_t)(bn + row) * 1024 + kt * 64 + swz, &Bs[b][c * 8]);
    }
  };
  auto COMPUTE = [&](int b) {
#pragma unroll
    for (int ks = 0; ks < 2; ++ks) {
      const int ck = ks * 4 + (lane >> 4);
      short8 af[4], bfr[4];
#pragma unroll
      for (int m = 0; m < 4; ++m) {
        int r = wr * 64 + m * 16 + (lane & 15);
        af[m] = *(const short8*)&As[(r * 8 + (ck ^ (r & 7))) * 8];
      }
#pragma unroll
      for (int n = 0; n < 4; ++n) {
        int r = wc * 64 + n * 16 + (lane & 15);
        bfr[n] = *(const short8*)&Bs[b][(r * 8 + (ck ^ (r & 7))) * 8];
      }
#pragma unroll
      for (int m = 0; m < 4; ++m)
#pragma unroll
        for (int n = 0; n < 4; ++n)
          acc[m][n] = __builtin_amdgcn_mfma_f32_16x16x32_bf16(af[m], bfr[n], acc[m][n], 0, 0, 0);
    }
  };

  STAGE_A(0, RA); STAGE_B(0, 0);
  STAGE_A(1, RB); STAGE_B(1, 1);
  for (int kt = 0; kt < 16; ++kt) {
    if (kt < 14) { WAIT_VM12(); } else { WAIT_VM0(); }
    if (kt & 1) WRITE_A(RB); else WRITE_A(RA);
    LGKM0_BAR();
    COMPUTE(kt & 1);
    BARRIER();
    if (kt < 14) {
      if (kt & 1) STAGE_A(kt + 2, RB); else STAGE_A(kt + 2, RA);
      STAGE_B(kt + 2, kt & 1);
    }
  }

  const int lrow4 = (lane >> 4) << 2;
  const int h = lane & 15;
  if (epi == 0) {
    const int dbase = (bn + wc * 64) >> 4;
#pragma unroll
    for (int m = 0; m < 4; ++m)
#pragma unroll
      for (int i = 0; i < 4; ++i) {
        int R = bm + wr * 64 + m * 16 + lrow4 + i;
        int b = R >> 11, l = R & 2047;
        u32 lo = (u32)bf16rne(acc[m][0][i] * ascale) | ((u32)bf16rne(acc[m][1][i] * ascale) << 16);
        u32 hi = (u32)bf16rne(acc[m][2][i] * ascale) | ((u32)bf16rne(acc[m][3][i] * ascale) << 16);
        size_t addr = ((size_t)((b * 16 + h) * 2048 + l)) * 64 + dbase;
        *(uint2*)(D + addr) = make_uint2(lo, hi);
      }
  } else {
    const int dbase = (bn + wc * 64) >> 4;
    const int b = bm >> 11;
#pragma unroll
    for (int m = 0; m < 4; ++m) {
      int l0 = (bm & 2047) + wr * 64 + m * 16 + lrow4;
#pragma unroll
      for (int n = 0; n < 4; ++n) {
        int d = dbase + n;
        u32 lo = (u32)bf16rne(acc[m][n][0]) | ((u32)bf16rne(acc[m][n][1]) << 16);
        u32 hi = (u32)bf16rne(acc[m][n][2]) | ((u32)bf16rne(acc[m][n][3]) << 16);
        size_t addr = ((size_t)((b * 16 + h) * 64 + d)) * 2048 + l0;
        *(uint2*)(D + addr) = make_uint2(lo, hi);
      }
    }
  }
}

// ---------------- O-projection GEMM (XCD-grouped flat grid, unchanged) ----------------
__global__ __launch_bounds__(256, 2) void gemm_oproj(const u16* __restrict__ A,
                                                     const u16* __restrict__ Bw,
                                                     float* __restrict__ C) {
  const int bid = blockIdx.x;
  const int slot = bid >> 3;                 // 0..31
  const int bm = ((bid & 7) * 4 + (slot >> 3)) * 128;
  const int bn = (slot & 7) * 128;
  const int tid = threadIdx.x, lane = tid & 63, w = tid >> 6;
  const int wr = w >> 1, wc = w & 1;
  __shared__ __align__(16) u16 As[2][128 * 64];
  __shared__ __align__(16) u16 Bs[2][128 * 64];
  f32x4 acc[4][4];
#pragma unroll
  for (int m = 0; m < 4; ++m)
#pragma unroll
    for (int n = 0; n < 4; ++n) acc[m][n] = (f32x4){0.f, 0.f, 0.f, 0.f};

  auto STAGE = [&](int kt, int b) {
#pragma unroll
    for (int i = 0; i < 4; ++i) {
      int c = tid + i * 256;
      int row = c >> 3, kc = c & 7;
      int swz = (kc ^ (row & 7)) << 3;
      int bA = bm >> 11;
      int lrow = (bm & 2047) + row;
      const u16* srcA = A + ((size_t)(bA * 16 + kt) * 2048 + lrow) * 64 + swz;
      gl_lds16(srcA, &As[b][c * 8]);
      const u16* srcB = Bw + (size_t)(bn + row) * 1024 + kt * 64 + swz;
      gl_lds16(srcB, &Bs[b][c * 8]);
    }
  };

  auto COMPUTE = [&](int b) {
#pragma unroll
    for (int ks = 0; ks < 2; ++ks) {
      const int ck = ks * 4 + (lane >> 4);
      short8 af[4], bfr[4];
#pragma unroll
      for (int m = 0; m < 4; ++m) {
        int r = wr * 64 + m * 16 + (lane & 15);
        af[m] = *(const short8*)&As[b][(r * 8 + (ck ^ (r & 7))) * 8];
      }
#pragma unroll
      for (int n = 0; n < 4; ++n) {
        int r = wc * 64 + n * 16 + (lane & 15);
        bfr[n] = *(const short8*)&Bs[b][(r * 8 + (ck ^ (r & 7))) * 8];
      }
#pragma unroll
      for (int m = 0; m < 4; ++m)
#pragma unroll
        for (int n = 0; n < 4; ++n)
          acc[m][n] = __builtin_amdgcn_mfma_f32_16x16x32_bf16(af[m], bfr[n], acc[m][n], 0, 0, 0);
    }
  };

  STAGE(0, 0);
  STAGE(1, 1);
  for (int kt = 0; kt < 15; ++kt) {
    WAIT_VM8();
    BARRIER();
    COMPUTE(kt & 1);
    BARRIER();
    if (kt < 14) STAGE(kt + 2, kt & 1);
  }
  WAIT_VM0();
  BARRIER();
  COMPUTE(1);

  const int lrow4 = (lane >> 4) << 2;
#pragma unroll
  for (int m = 0; m < 4; ++m)
#pragma unroll
    for (int i = 0; i < 4; ++i) {
      int R = bm + wr * 64 + m * 16 + lrow4 + i;
      size_t base = (size_t)R * 1024 + bn + wc * 64 + (lane & 15);
#pragma unroll
      for (int n = 0; n < 4; ++n) C[base + n * 16] = acc[m][n][i];
    }
}

// ---------------- flash attention (unchanged from R11) ----------------
__global__ __launch_bounds__(128, 2) void attn_kernel(const u16* __restrict__ Qh,
                                                      const u16* __restrict__ Kh,
                                                      const u16* __restrict__ Vt,
                                                      u16* __restrict__ Oh) {
  const int hb = blockIdx.x;
  const int qt = blockIdx.y;
  const int tid = threadIdx.x, lane = tid & 63, w = tid >> 6;
  const int l31 = lane & 31, hi = lane >> 5;
  __shared__ __align__(16) u16 Ks[2][64 * 64];
  __shared__ __align__(16) u16 Vs[3][64 * 64];

  const u16* Qg = Qh + (size_t)hb * (2048 * 64);
  const u16* Kg = Kh + (size_t)hb * (2048 * 64);
  const u16* Vg = Vt + (size_t)hb * (64 * 2048);
  const int qrow = qt * 64 + w * 32 + l31;

  short8 qf[4];
#pragma unroll
  for (int ks = 0; ks < 4; ++ks)
    qf[ks] = *(const short8*)(Qg + (size_t)qrow * 64 + ks * 16 + hi * 8);

  int rs[4], sw[4];
#pragma unroll
  for (int i = 0; i < 4; ++i) {
    int c = tid + i * 128;
    rs[i] = c >> 3;
    sw[i] = (((c & 7) ^ FSWZ(rs[i])) << 3);
  }

  auto STAGE_K = [&](int t, int slot) {
    const size_t ko = (size_t)t * (64 * 64);
#pragma unroll
    for (int i = 0; i < 4; ++i) {
      int c = tid + i * 128;
      gl_lds16(Kg + ko + (size_t)rs[i] * 64 + sw[i], &Ks[slot][c * 8]);
    }
  };
  auto STAGE_V = [&](int t, int slot) {
    const int vo = t * 64;
#pragma unroll
    for (int i = 0; i < 4; ++i) {
      int c = tid + i * 128;
      gl_lds16(Vg + (size_t)rs[i] * 2048 + vo + sw[i], &Vs[slot][c * 8]);
    }
  };

  f32x16 oacc0, oacc1, SA0, SA1, SB0, SB1;
#pragma unroll
  for (int i = 0; i < 16; ++i) { oacc0[i] = 0.f; oacc1[i] = 0.f; }
  u32 pkA[16], pkB[16];
  float lrow = 0.f;

  auto QKT = [&](int kslot, f32x16& s0, f32x16& s1) {
#pragma unroll
    for (int i = 0; i < 16; ++i) { s0[i] = 0.f; s1[i] = 0.f; }
    __builtin_amdgcn_s_setprio(1);
#pragma unroll
    for (int ks = 0; ks < 4; ++ks) {
      const int ck = 2 * ks + hi;
      const int r0 = l31, r1 = 32 + l31;
      short8 k0 = *(const short8*)&Ks[kslot][(r0 * 8 + (ck ^ FSWZ(r0))) * 8];
      short8 k1 = *(const short8*)&Ks[kslot][(r1 * 8 + (ck ^ FSWZ(r1))) * 8];
      s0 = __builtin_amdgcn_mfma_f32_32x32x16_bf16(k0, qf[ks], s0, 0, 0, 0);
      s1 = __builtin_amdgcn_mfma_f32_32x32x16_bf16(k1, qf[ks], s1, 0, 0, 0);
    }
    __builtin_amdgcn_s_setprio(0);
  };

  auto PV = [&](const u32* pk, int vslot) {
    __builtin_amdgcn_s_setprio(1);
#pragma unroll
    for (int c = 0; c < 4; ++c) {
      union { u32 wu[4]; short8 v; } un;
      un.wu[0] = pk[c * 4 + 0]; un.wu[1] = pk[c * 4 + 1];
      un.wu[2] = pk[c * 4 + 2]; un.wu[3] = pk[c * 4 + 3];
      const int ckv = 2 * c + hi;
      const int rv0 = l31, rv1 = 32 + l31;
      short8 v0 = *(const short8*)&Vs[vslot][(rv0 * 8 + (ckv ^ FSWZ(rv0))) * 8];
      short8 v1 = *(const short8*)&Vs[vslot][(rv1 * 8 + (ckv ^ FSWZ(rv1))) * 8];
      oacc0 = __builtin_amdgcn_mfma_f32_32x32x16_bf16(v0, un.v, oacc0, 0, 0, 0);
      oacc1 = __builtin_amdgcn_mfma_f32_32x32x16_bf16(v1, un.v, oacc1, 0, 0, 0);
    }
    __builtin_amdgcn_s_setprio(0);
  };

  auto SOFTMAX = [&](f32x16& s0, f32x16& s1, u32* pk) {
#pragma unroll
    for (int i = 0; i < 16; ++i) {
      s0[i] = __builtin_amdgcn_exp2f(s0[i]);
      s1[i] = __builtin_amdgcn_exp2f(s1[i]);
    }
    f32x16 a01 = s0 + s1;
    float r8[8];
#pragma unroll
    for (int i = 0; i < 8; ++i) r8[i] = a01[i] + a01[i + 8];
#pragma unroll
    for (int i = 0; i < 4; ++i) r8[i] += r8[i + 4];
    float rsum = (r8[0] + r8[1]) + (r8[2] + r8[3]);
    int2v pr = __builtin_amdgcn_permlane32_swap(__builtin_bit_cast(int, rsum),
                                                __builtin_bit_cast(int, rsum), false, false);
    lrow += __builtin_bit_cast(float, pr[0]) + __builtin_bit_cast(float, pr[1]);
#pragma unroll
    for (int c = 0; c < 4; ++c) {
      float pe0, pe1, pe2, pe3, pe4, pe5, pe6, pe7;
      if (c < 2) {
        const int s8 = (c & 1) * 8;
        pe0 = s0[s8 + 0]; pe1 = s0[s8 + 1]; pe2 = s0[s8 + 2]; pe3 = s0[s8 + 3];
        pe4 = s0[s8 + 4]; pe5 = s0[s8 + 5]; pe6 = s0[s8 + 6]; pe7 = s0[s8 + 7];
      } else {
        const int s8 = (c & 1) * 8;
        pe0 = s1[s8 + 0]; pe1 = s1[s8 + 1]; pe2 = s1[s8 + 2]; pe3 = s1[s8 + 3];
        pe4 = s1[s8 + 4]; pe5 = s1[s8 + 5]; pe6 = s1[s8 + 6]; pe7 = s1[s8 + 7];
      }
      u32 a0 = cvtpk(pe0, pe1), a1 = cvtpk(pe2, pe3);
      u32 a2 = cvtpk(pe4, pe5), a3 = cvtpk(pe6, pe7);
      int2v w02 = __builtin_amdgcn_permlane32_swap((int)a0, (int)a2, false, false);
      int2v w13 = __builtin_amdgcn_permlane32_swap((int)a1, (int)a3, false, false);
      pk[c * 4 + 0] = (u32)w02[0]; pk[c * 4 + 1] = (u32)w13[0];
      pk[c * 4 + 2] = (u32)w02[1]; pk[c * 4 + 3] = (u32)w13[1];
    }
  };

  // ---- prologue ----
  STAGE_K(0, 0); STAGE_K(1, 1); STAGE_V(0, 0);
  WAIT_VM8(); BARRIER();
  QKT(0, SA0, SA1);
  BARRIER();
  STAGE_K(2, 0); STAGE_V(1, 1);
  WAIT_VM8(); BARRIER();
  QKT(1, SB0, SB1);
  SOFTMAX(SA0, SA1, pkB);
  BARRIER();
  STAGE_K(3, 1); STAGE_V(2, 2);

  // ---- steady state: QKT(i) || PV(i-2) || SOFTMAX(i-1) ----
  for (int i = 2; i < 32; i += 2) {
    WAIT_VM8(); BARRIER();
    QKT(0, SA0, SA1);
    PV(pkB, (i - 2) % 3);
    SOFTMAX(SB0, SB1, pkA);
    BARRIER();
    if (i + 2 <= 31) STAGE_K(i + 2, 0);
    STAGE_V(i + 1, (i + 1) % 3);
    WAIT_VM8(); BARRIER();
    QKT(1, SB0, SB1);
    PV(pkA, (i - 1) % 3);
    SOFTMAX(SA0, SA1, pkB);
    BARRIER();
    if (i + 3 <= 31) STAGE_K(i + 3, 1);
    if (i + 2 <= 31) STAGE_V(i + 2, (i + 2) % 3);
  }

  // ---- epilogue ----
  WAIT_VM0(); BARRIER();
  SOFTMAX(SB0, SB1, pkA);
  PV(pkB, 30 % 3);
  PV(pkA, 31 % 3);

  const float inv = 1.0f / lrow;
  u16* Og = Oh + (size_t)hb * (2048 * 64) + (size_t)qrow * 64;
#pragma unroll
  for (int dblk = 0; dblk < 2; ++dblk) {
#pragma unroll
    for (int r = 0; r < 16; r += 2) {
      const int d = dblk * 32 + (r & 3) + 8 * (r >> 2) + 4 * hi;
      float v0 = (dblk ? oacc1[r] : oacc0[r]) * inv;
      float v1 = (dblk ? oacc1[r + 1] : oacc0[r + 1]) * inv;
      *(u32*)(Og + d) = (u32)bf16rne(v0) | ((u32)bf16rne(v1) << 16);
    }
  }
}

// ---------------- launch ----------------
extern "C" void kernel_launch(void* const* d_in, const int* in_sizes, int n_in,
                              void* d_out, int out_size, void* d_ws, size_t ws_size,
                              hipStream_t stream) {
  const float* q = (const float*)d_in[0];
  const float* k = (const float*)d_in[1];
  const float* v = (const float*)d_in[2];
  const float* WQ = (const float*)d_in[3];
  const float* WK = (const float*)d_in[4];
  const float* WV = (const float*)d_in[5];
  const float* WO = (const float*)d_in[6];
  float* out = (float*)d_out;
  char* ws = (char*)d_ws;
  const size_t MB = 1024 * 1024;
  if (ws_size < 64 * MB) return;

  u16* WQb = (u16*)(ws + 24 * MB);
  u16* WKb = (u16*)(ws + 26 * MB);
  u16* WVb = (u16*)(ws + 28 * MB);
  u16* WOt = (u16*)(ws + 30 * MB);
  u16* Qh  = (u16*)(ws + 32 * MB);
  u16* Kh  = (u16*)(ws + 40 * MB);
  u16* Vt  = (u16*)(ws + 48 * MB);
  u16* Ohd = (u16*)(ws + 56 * MB);

  CastArgs ca;
  ca.src[0] = WQ; ca.dst[0] = WQb; ca.n4[0] = (1024 * 1024) / 4;
  ca.src[1] = WK; ca.dst[1] = WKb; ca.n4[1] = (1024 * 1024) / 4;
  ca.src[2] = WV; ca.dst[2] = WVb; ca.n4[2] = (1024 * 1024) / 4;
  ca.src[3] = WO; ca.dst[3] = WOt; ca.n4[3] = 1024 * 1024;
  cast_all<<<dim3(128, 4), 256, 0, stream>>>(ca);

  ProjFArgs pa;
  pa.A[0] = q; pa.W[0] = WQb; pa.D[0] = Qh;  pa.scale[0] = 0.18033688011f; // 1/8*log2(e)
  pa.A[1] = k; pa.W[1] = WKb; pa.D[1] = Kh;  pa.scale[1] = 1.0f;
  pa.A[2] = v; pa.W[2] = WVb; pa.D[2] = Vt;  pa.scale[2] = 1.0f;
  gemm_projf<<<768, 256, 0, stream>>>(pa);

  attn_kernel<<<dim3(32, 32), 128, 0, stream>>>(Qh, Kh, Vt, Ohd);

  gemm_oproj<<<256, 256, 0, stream>>>(Ohd, WOt, out);
}

// Round 13
// 126.743 us; speedup vs baseline: 1.1490x; 1.1490x over previous
//
#include <hip/hip_runtime.h>
#include <hip/hip_bf16.h>
#include <stdint.h>

typedef __attribute__((ext_vector_type(8))) short short8;
typedef __attribute__((ext_vector_type(4))) float f32x4;
typedef __attribute__((ext_vector_type(16))) float f32x16;
typedef __attribute__((ext_vector_type(2))) int int2v;
typedef unsigned short u16;
typedef unsigned int u32;

// B=2, H=16, L=2048, Dh=64, Dm=1024, M=B*L=4096, K=1024

#define WAIT_VM12() do { asm volatile("s_waitcnt vmcnt(12)" ::: "memory"); \
                         __builtin_amdgcn_sched_barrier(0); } while (0)
#define WAIT_VM8()  do { asm volatile("s_waitcnt vmcnt(8)" ::: "memory"); \
                         __builtin_amdgcn_sched_barrier(0); } while (0)
#define WAIT_VM0()  do { asm volatile("s_waitcnt vmcnt(0)" ::: "memory"); \
                         __builtin_amdgcn_sched_barrier(0); } while (0)
#define BARRIER()   do { __builtin_amdgcn_s_barrier(); \
                         __builtin_amdgcn_sched_barrier(0); } while (0)
#define LGKM0_BAR() do { asm volatile("s_waitcnt lgkmcnt(0)" ::: "memory"); \
                         __builtin_amdgcn_s_barrier(); \
                         __builtin_amdgcn_sched_barrier(0); } while (0)

// LDS row swizzle: 2-way max bank aliasing (conflict-free, validated R11)
#define FSWZ(r) (((r) ^ ((r) >> 3)) & 7)

__device__ __forceinline__ u16 bf16rne(float f) {
  u32 u = __builtin_bit_cast(u32, f);
  u += 0x7FFFu + ((u >> 16) & 1u);
  return (u16)(u >> 16);
}

__device__ __forceinline__ u32 cvtpk(float lo, float hi) {
  u32 r;
  asm("v_cvt_pk_bf16_f32 %0, %1, %2" : "=v"(r) : "v"(lo), "v"(hi));
  return r;
}

__device__ __forceinline__ void gl_lds16(const u16* g, u16* l) {
  __builtin_amdgcn_global_load_lds((const __attribute__((address_space(1))) void*)g,
                                   (__attribute__((address_space(3))) void*)l, 16, 0, 0);
}

// ---------------- cast kernel (weights only) ----------------
struct CastArgs {
  const float* src[4];
  u16* dst[4];
  int n4[4];
};

__global__ void cast_all(CastArgs a) {
  const int id = blockIdx.y;
  const float* __restrict__ s = a.src[id];
  u16* __restrict__ d = a.dst[id];
  const int stride = gridDim.x * blockDim.x;
  const int i0 = blockIdx.x * blockDim.x + threadIdx.x;
  if (id < 3) {
    const int n4 = a.n4[id];
    for (int i = i0; i < n4; i += stride) {
      float4 v = ((const float4*)s)[i];
      u32 lo = (u32)bf16rne(v.x) | ((u32)bf16rne(v.y) << 16);
      u32 hi = (u32)bf16rne(v.z) | ((u32)bf16rne(v.w) << 16);
      ((uint2*)d)[i] = make_uint2(lo, hi);
    }
  } else {
    // W_O permute: dst[n][h*64+dd] = src[n][dd*16+h]
    const int n = a.n4[3];
    for (int i = i0; i < n; i += stride) {
      int row = i >> 10, c = i & 1023;
      int hh = c >> 6, dd = c & 63;
      d[i] = bf16rne(s[(row << 10) + dd * 16 + hh]);
    }
  }
}

// ---------------- fused cast+GEMM: R11 loop structure, As SINGLE-buffered ----------------
// As[1] 16KB + Bs[2] 32KB = 48KB -> 3 blocks/CU; 768 blocks = exactly 3/CU (no tail round).
// Post-COMPUTE barrier orders WRITE_A against previous tile's reads (2 barriers/tile).
struct ProjFArgs { const float* A[3]; const u16* W[3]; u16* D[3]; float scale[3]; };

__global__ __launch_bounds__(256, 2) void gemm_projf(ProjFArgs pa) {
  const int bid = blockIdx.x;                       // 0..767
  const int grp = ((bid >> 6) << 3) | (bid & 7);    // (proj,bm) group, same XCD for its 8 bn
  const int bn = ((bid >> 3) & 7) * 128;
  const int z = grp >> 5;
  const int bm = (grp & 31) * 128;
  const float* __restrict__ A = pa.A[z];
  const u16* __restrict__ Bw = pa.W[z];
  u16* __restrict__ D = pa.D[z];
  const float ascale = pa.scale[z];
  const int epi = (z == 2) ? 1 : 0;

  const int tid = threadIdx.x, lane = tid & 63, w = tid >> 6;
  const int wr = w >> 1, wc = w & 1;
  __shared__ __align__(16) u16 As[128 * 64];        // single buffer: RA/RB regs are buffer 2
  __shared__ __align__(16) u16 Bs[2][128 * 64];

  f32x4 acc[4][4];
#pragma unroll
  for (int m = 0; m < 4; ++m)
#pragma unroll
    for (int n = 0; n < 4; ++n) acc[m][n] = (f32x4){0.f, 0.f, 0.f, 0.f};

  struct ARegs { float4 v[8]; };
  ARegs RA, RB;

  auto STAGE_A = [&](int kt, ARegs& R) {
#pragma unroll
    for (int i = 0; i < 4; ++i) {
      int c = tid + i * 256;
      int row = c >> 3;
      int col = (((c & 7) ^ (row & 7)) << 3);
      const float* src = A + (size_t)(bm + row) * 1024 + kt * 64 + col;
      R.v[2 * i] = *(const float4*)(src);
      R.v[2 * i + 1] = *(const float4*)(src + 4);
    }
  };
  auto WRITE_A = [&](ARegs& R) {
#pragma unroll
    for (int i = 0; i < 4; ++i) {
      int c = tid + i * 256;
      u32 p0 = (u32)bf16rne(R.v[2 * i].x) | ((u32)bf16rne(R.v[2 * i].y) << 16);
      u32 p1 = (u32)bf16rne(R.v[2 * i].z) | ((u32)bf16rne(R.v[2 * i].w) << 16);
      u32 p2 = (u32)bf16rne(R.v[2 * i + 1].x) | ((u32)bf16rne(R.v[2 * i + 1].y) << 16);
      u32 p3 = (u32)bf16rne(R.v[2 * i + 1].z) | ((u32)bf16rne(R.v[2 * i + 1].w) << 16);
      *(uint4*)&As[c * 8] = make_uint4(p0, p1, p2, p3);
    }
  };
  auto STAGE_B = [&](int kt, int b) {
#pragma unroll
    for (int i = 0; i < 4; ++i) {
      int c = tid + i * 256;
      int row = c >> 3;
      int swz = (((c & 7) ^ (row & 7)) << 3);
      gl_lds16(Bw + (size_t)(bn + row) * 1024 + kt * 64 + swz, &Bs[b][c * 8]);
    }
  };
  auto COMPUTE = [&](int b) {
#pragma unroll
    for (int ks = 0; ks < 2; ++ks) {
      const int ck = ks * 4 + (lane >> 4);
      short8 af[4], bfr[4];
#pragma unroll
      for (int m = 0; m < 4; ++m) {
        int r = wr * 64 + m * 16 + (lane & 15);
        af[m] = *(const short8*)&As[(r * 8 + (ck ^ (r & 7))) * 8];
      }
#pragma unroll
      for (int n = 0; n < 4; ++n) {
        int r = wc * 64 + n * 16 + (lane & 15);
        bfr[n] = *(const short8*)&Bs[b][(r * 8 + (ck ^ (r & 7))) * 8];
      }
#pragma unroll
      for (int m = 0; m < 4; ++m)
#pragma unroll
        for (int n = 0; n < 4; ++n)
          acc[m][n] = __builtin_amdgcn_mfma_f32_16x16x32_bf16(af[m], bfr[n], acc[m][n], 0, 0, 0);
    }
  };

  // ---- pipeline: R11 structure (explicit x2 unroll, static RA/RB), single As ----
  STAGE_A(0, RA); STAGE_B(0, 0);
  STAGE_A(1, RB); STAGE_B(1, 1);
  for (int k2 = 0; k2 < 7; ++k2) {
    const int kt = 2 * k2;
    WAIT_VM12();
    WRITE_A(RA); LGKM0_BAR();
    COMPUTE(0); BARRIER();
    STAGE_A(kt + 2, RA); STAGE_B(kt + 2, 0);
    WAIT_VM12();
    WRITE_A(RB); LGKM0_BAR();
    COMPUTE(1); BARRIER();
    STAGE_A(kt + 3, RB); STAGE_B(kt + 3, 1);
  }
  // kt = 14
  WAIT_VM12();
  WRITE_A(RA); LGKM0_BAR();
  COMPUTE(0); BARRIER();
  // kt = 15
  WAIT_VM0();
  WRITE_A(RB); LGKM0_BAR();
  COMPUTE(1);

  const int lrow4 = (lane >> 4) << 2;
  const int h = lane & 15;
  if (epi == 0) {
    const int dbase = (bn + wc * 64) >> 4;
#pragma unroll
    for (int m = 0; m < 4; ++m)
#pragma unroll
      for (int i = 0; i < 4; ++i) {
        int R = bm + wr * 64 + m * 16 + lrow4 + i;
        int b = R >> 11, l = R & 2047;
        u32 lo = (u32)bf16rne(acc[m][0][i] * ascale) | ((u32)bf16rne(acc[m][1][i] * ascale) << 16);
        u32 hi = (u32)bf16rne(acc[m][2][i] * ascale) | ((u32)bf16rne(acc[m][3][i] * ascale) << 16);
        size_t addr = ((size_t)((b * 16 + h) * 2048 + l)) * 64 + dbase;
        *(uint2*)(D + addr) = make_uint2(lo, hi);
      }
  } else {
    const int dbase = (bn + wc * 64) >> 4;
    const int b = bm >> 11;
#pragma unroll
    for (int m = 0; m < 4; ++m) {
      int l0 = (bm & 2047) + wr * 64 + m * 16 + lrow4;
#pragma unroll
      for (int n = 0; n < 4; ++n) {
        int d = dbase + n;
        u32 lo = (u32)bf16rne(acc[m][n][0]) | ((u32)bf16rne(acc[m][n][1]) << 16);
        u32 hi = (u32)bf16rne(acc[m][n][2]) | ((u32)bf16rne(acc[m][n][3]) << 16);
        size_t addr = ((size_t)((b * 16 + h) * 64 + d)) * 2048 + l0;
        *(uint2*)(D + addr) = make_uint2(lo, hi);
      }
    }
  }
}

// ---------------- O-projection GEMM (XCD-grouped flat grid, unchanged) ----------------
__global__ __launch_bounds__(256, 2) void gemm_oproj(const u16* __restrict__ A,
                                                     const u16* __restrict__ Bw,
                                                     float* __restrict__ C) {
  const int bid = blockIdx.x;
  const int slot = bid >> 3;                 // 0..31
  const int bm = ((bid & 7) * 4 + (slot >> 3)) * 128;
  const int bn = (slot & 7) * 128;
  const int tid = threadIdx.x, lane = tid & 63, w = tid >> 6;
  const int wr = w >> 1, wc = w & 1;
  __shared__ __align__(16) u16 As[2][128 * 64];
  __shared__ __align__(16) u16 Bs[2][128 * 64];
  f32x4 acc[4][4];
#pragma unroll
  for (int m = 0; m < 4; ++m)
#pragma unroll
    for (int n = 0; n < 4; ++n) acc[m][n] = (f32x4){0.f, 0.f, 0.f, 0.f};

  auto STAGE = [&](int kt, int b) {
#pragma unroll
    for (int i = 0; i < 4; ++i) {
      int c = tid + i * 256;
      int row = c >> 3, kc = c & 7;
      int swz = (kc ^ (row & 7)) << 3;
      int bA = bm >> 11;
      int lrow = (bm & 2047) + row;
      const u16* srcA = A + ((size_t)(bA * 16 + kt) * 2048 + lrow) * 64 + swz;
      gl_lds16(srcA, &As[b][c * 8]);
      const u16* srcB = Bw + (size_t)(bn + row) * 1024 + kt * 64 + swz;
      gl_lds16(srcB, &Bs[b][c * 8]);
    }
  };

  auto COMPUTE = [&](int b) {
#pragma unroll
    for (int ks = 0; ks < 2; ++ks) {
      const int ck = ks * 4 + (lane >> 4);
      short8 af[4], bfr[4];
#pragma unroll
      for (int m = 0; m < 4; ++m) {
        int r = wr * 64 + m * 16 + (lane & 15);
        af[m] = *(const short8*)&As[b][(r * 8 + (ck ^ (r & 7))) * 8];
      }
#pragma unroll
      for (int n = 0; n < 4; ++n) {
        int r = wc * 64 + n * 16 + (lane & 15);
        bfr[n] = *(const short8*)&Bs[b][(r * 8 + (ck ^ (r & 7))) * 8];
      }
#pragma unroll
      for (int m = 0; m < 4; ++m)
#pragma unroll
        for (int n = 0; n < 4; ++n)
          acc[m][n] = __builtin_amdgcn_mfma_f32_16x16x32_bf16(af[m], bfr[n], acc[m][n], 0, 0, 0);
    }
  };

  STAGE(0, 0);
  STAGE(1, 1);
  for (int kt = 0; kt < 15; ++kt) {
    WAIT_VM8();
    BARRIER();
    COMPUTE(kt & 1);
    BARRIER();
    if (kt < 14) STAGE(kt + 2, kt & 1);
  }
  WAIT_VM0();
  BARRIER();
  COMPUTE(1);

  const int lrow4 = (lane >> 4) << 2;
#pragma unroll
  for (int m = 0; m < 4; ++m)
#pragma unroll
    for (int i = 0; i < 4; ++i) {
      int R = bm + wr * 64 + m * 16 + lrow4 + i;
      size_t base = (size_t)R * 1024 + bn + wc * 64 + (lane & 15);
#pragma unroll
      for (int n = 0; n < 4; ++n) C[base + n * 16] = acc[m][n][i];
    }
}

// ---------------- flash attention (unchanged from R11) ----------------
__global__ __launch_bounds__(128, 2) void attn_kernel(const u16* __restrict__ Qh,
                                                      const u16* __restrict__ Kh,
                                                      const u16* __restrict__ Vt,
                                                      u16* __restrict__ Oh) {
  const int hb = blockIdx.x;
  const int qt = blockIdx.y;
  const int tid = threadIdx.x, lane = tid & 63, w = tid >> 6;
  const int l31 = lane & 31, hi = lane >> 5;
  __shared__ __align__(16) u16 Ks[2][64 * 64];
  __shared__ __align__(16) u16 Vs[3][64 * 64];

  const u16* Qg = Qh + (size_t)hb * (2048 * 64);
  const u16* Kg = Kh + (size_t)hb * (2048 * 64);
  const u16* Vg = Vt + (size_t)hb * (64 * 2048);
  const int qrow = qt * 64 + w * 32 + l31;

  short8 qf[4];
#pragma unroll
  for (int ks = 0; ks < 4; ++ks)
    qf[ks] = *(const short8*)(Qg + (size_t)qrow * 64 + ks * 16 + hi * 8);

  int rs[4], sw[4];
#pragma unroll
  for (int i = 0; i < 4; ++i) {
    int c = tid + i * 128;
    rs[i] = c >> 3;
    sw[i] = (((c & 7) ^ FSWZ(rs[i])) << 3);
  }

  auto STAGE_K = [&](int t, int slot) {
    const size_t ko = (size_t)t * (64 * 64);
#pragma unroll
    for (int i = 0; i < 4; ++i) {
      int c = tid + i * 128;
      gl_lds16(Kg + ko + (size_t)rs[i] * 64 + sw[i], &Ks[slot][c * 8]);
    }
  };
  auto STAGE_V = [&](int t, int slot) {
    const int vo = t * 64;
#pragma unroll
    for (int i = 0; i < 4; ++i) {
      int c = tid + i * 128;
      gl_lds16(Vg + (size_t)rs[i] * 2048 + vo + sw[i], &Vs[slot][c * 8]);
    }
  };

  f32x16 oacc0, oacc1, SA0, SA1, SB0, SB1;
#pragma unroll
  for (int i = 0; i < 16; ++i) { oacc0[i] = 0.f; oacc1[i] = 0.f; }
  u32 pkA[16], pkB[16];
  float lrow = 0.f;

  auto QKT = [&](int kslot, f32x16& s0, f32x16& s1) {
#pragma unroll
    for (int i = 0; i < 16; ++i) { s0[i] = 0.f; s1[i] = 0.f; }
    __builtin_amdgcn_s_setprio(1);
#pragma unroll
    for (int ks = 0; ks < 4; ++ks) {
      const int ck = 2 * ks + hi;
      const int r0 = l31, r1 = 32 + l31;
      short8 k0 = *(const short8*)&Ks[kslot][(r0 * 8 + (ck ^ FSWZ(r0))) * 8];
      short8 k1 = *(const short8*)&Ks[kslot][(r1 * 8 + (ck ^ FSWZ(r1))) * 8];
      s0 = __builtin_amdgcn_mfma_f32_32x32x16_bf16(k0, qf[ks], s0, 0, 0, 0);
      s1 = __builtin_amdgcn_mfma_f32_32x32x16_bf16(k1, qf[ks], s1, 0, 0, 0);
    }
    __builtin_amdgcn_s_setprio(0);
  };

  auto PV = [&](const u32* pk, int vslot) {
    __builtin_amdgcn_s_setprio(1);
#pragma unroll
    for (int c = 0; c < 4; ++c) {
      union { u32 wu[4]; short8 v; } un;
      un.wu[0] = pk[c * 4 + 0]; un.wu[1] = pk[c * 4 + 1];
      un.wu[2] = pk[c * 4 + 2]; un.wu[3] = pk[c * 4 + 3];
      const int ckv = 2 * c + hi;
      const int rv0 = l31, rv1 = 32 + l31;
      short8 v0 = *(const short8*)&Vs[vslot][(rv0 * 8 + (ckv ^ FSWZ(rv0))) * 8];
      short8 v1 = *(const short8*)&Vs[vslot][(rv1 * 8 + (ckv ^ FSWZ(rv1))) * 8];
      oacc0 = __builtin_amdgcn_mfma_f32_32x32x16_bf16(v0, un.v, oacc0, 0, 0, 0);
      oacc1 = __builtin_amdgcn_mfma_f32_32x32x16_bf16(v1, un.v, oacc1, 0, 0, 0);
    }
    __builtin_amdgcn_s_setprio(0);
  };

  auto SOFTMAX = [&](f32x16& s0, f32x16& s1, u32* pk) {
#pragma unroll
    for (int i = 0; i < 16; ++i) {
      s0[i] = __builtin_amdgcn_exp2f(s0[i]);
      s1[i] = __builtin_amdgcn_exp2f(s1[i]);
    }
    f32x16 a01 = s0 + s1;
    float r8[8];
#pragma unroll
    for (int i = 0; i < 8; ++i) r8[i] = a01[i] + a01[i + 8];
#pragma unroll
    for (int i = 0; i < 4; ++i) r8[i] += r8[i + 4];
    float rsum = (r8[0] + r8[1]) + (r8[2] + r8[3]);
    int2v pr = __builtin_amdgcn_permlane32_swap(__builtin_bit_cast(int, rsum),
                                                __builtin_bit_cast(int, rsum), false, false);
    lrow += __builtin_bit_cast(float, pr[0]) + __builtin_bit_cast(float, pr[1]);
#pragma unroll
    for (int c = 0; c < 4; ++c) {
      float pe0, pe1, pe2, pe3, pe4, pe5, pe6, pe7;
      if (c < 2) {
        const int s8 = (c & 1) * 8;
        pe0 = s0[s8 + 0]; pe1 = s0[s8 + 1]; pe2 = s0[s8 + 2]; pe3 = s0[s8 + 3];
        pe4 = s0[s8 + 4]; pe5 = s0[s8 + 5]; pe6 = s0[s8 + 6]; pe7 = s0[s8 + 7];
      } else {
        const int s8 = (c & 1) * 8;
        pe0 = s1[s8 + 0]; pe1 = s1[s8 + 1]; pe2 = s1[s8 + 2]; pe3 = s1[s8 + 3];
        pe4 = s1[s8 + 4]; pe5 = s1[s8 + 5]; pe6 = s1[s8 + 6]; pe7 = s1[s8 + 7];
      }
      u32 a0 = cvtpk(pe0, pe1), a1 = cvtpk(pe2, pe3);
      u32 a2 = cvtpk(pe4, pe5), a3 = cvtpk(pe6, pe7);
      int2v w02 = __builtin_amdgcn_permlane32_swap((int)a0, (int)a2, false, false);
      int2v w13 = __builtin_amdgcn_permlane32_swap((int)a1, (int)a3, false, false);
      pk[c * 4 + 0] = (u32)w02[0]; pk[c * 4 + 1] = (u32)w13[0];
      pk[c * 4 + 2] = (u32)w02[1]; pk[c * 4 + 3] = (u32)w13[1];
    }
  };

  // ---- prologue ----
  STAGE_K(0, 0); STAGE_K(1, 1); STAGE_V(0, 0);
  WAIT_VM8(); BARRIER();
  QKT(0, SA0, SA1);
  BARRIER();
  STAGE_K(2, 0); STAGE_V(1, 1);
  WAIT_VM8(); BARRIER();
  QKT(1, SB0, SB1);
  SOFTMAX(SA0, SA1, pkB);
  BARRIER();
  STAGE_K(3, 1); STAGE_V(2, 2);

  // ---- steady state: QKT(i) || PV(i-2) || SOFTMAX(i-1) ----
  for (int i = 2; i < 32; i += 2) {
    WAIT_VM8(); BARRIER();
    QKT(0, SA0, SA1);
    PV(pkB, (i - 2) % 3);
    SOFTMAX(SB0, SB1, pkA);
    BARRIER();
    if (i + 2 <= 31) STAGE_K(i + 2, 0);
    STAGE_V(i + 1, (i + 1) % 3);
    WAIT_VM8(); BARRIER();
    QKT(1, SB0, SB1);
    PV(pkA, (i - 1) % 3);
    SOFTMAX(SA0, SA1, pkB);
    BARRIER();
    if (i + 3 <= 31) STAGE_K(i + 3, 1);
    if (i + 2 <= 31) STAGE_V(i + 2, (i + 2) % 3);
  }

  // ---- epilogue ----
  WAIT_VM0(); BARRIER();
  SOFTMAX(SB0, SB1, pkA);
  PV(pkB, 30 % 3);
  PV(pkA, 31 % 3);

  const float inv = 1.0f / lrow;
  u16* Og = Oh + (size_t)hb * (2048 * 64) + (size_t)qrow * 64;
#pragma unroll
  for (int dblk = 0; dblk < 2; ++dblk) {
#pragma unroll
    for (int r = 0; r < 16; r += 2) {
      const int d = dblk * 32 + (r & 3) + 8 * (r >> 2) + 4 * hi;
      float v0 = (dblk ? oacc1[r] : oacc0[r]) * inv;
      float v1 = (dblk ? oacc1[r + 1] : oacc0[r + 1]) * inv;
      *(u32*)(Og + d) = (u32)bf16rne(v0) | ((u32)bf16rne(v1) << 16);
    }
  }
}

// ---------------- launch ----------------
extern "C" void kernel_launch(void* const* d_in, const int* in_sizes, int n_in,
                              void* d_out, int out_size, void* d_ws, size_t ws_size,
                              hipStream_t stream) {
  const float* q = (const float*)d_in[0];
  const float* k = (const float*)d_in[1];
  const float* v = (const float*)d_in[2];
  const float* WQ = (const float*)d_in[3];
  const float* WK = (const float*)d_in[4];
  const float* WV = (const float*)d_in[5];
  const float* WO = (const float*)d_in[6];
  float* out = (float*)d_out;
  char* ws = (char*)d_ws;
  const size_t MB = 1024 * 1024;
  if (ws_size < 64 * MB) return;

  u16* WQb = (u16*)(ws + 24 * MB);
  u16* WKb = (u16*)(ws + 26 * MB);
  u16* WVb = (u16*)(ws + 28 * MB);
  u16* WOt = (u16*)(ws + 30 * MB);
  u16* Qh  = (u16*)(ws + 32 * MB);
  u16* Kh  = (u16*)(ws + 40 * MB);
  u16* Vt  = (u16*)(ws + 48 * MB);
  u16* Ohd = (u16*)(ws + 56 * MB);

  CastArgs ca;
  ca.src[0] = WQ; ca.dst[0] = WQb; ca.n4[0] = (1024 * 1024) / 4;
  ca.src[1] = WK; ca.dst[1] = WKb; ca.n4[1] = (1024 * 1024) / 4;
  ca.src[2] = WV; ca.dst[2] = WVb; ca.n4[2] = (1024 * 1024) / 4;
  ca.src[3] = WO; ca.dst[3] = WOt; ca.n4[3] = 1024 * 1024;
  cast_all<<<dim3(128, 4), 256, 0, stream>>>(ca);

  ProjFArgs pa;
  pa.A[0] = q; pa.W[0] = WQb; pa.D[0] = Qh;  pa.scale[0] = 0.18033688011f; // 1/8*log2(e)
  pa.A[1] = k; pa.W[1] = WKb; pa.D[1] = Kh;  pa.scale[1] = 1.0f;
  pa.A[2] = v; pa.W[2] = WVb; pa.D[2] = Vt;  pa.scale[2] = 1.0f;
  gemm_projf<<<768, 256, 0, stream>>>(pa);

  attn_kernel<<<dim3(32, 32), 128, 0, stream>>>(Qh, Kh, Vt, Ohd);

  gemm_oproj<<<256, 256, 0, stream>>>(Ohd, WOt, out);
}